// Round 3
// baseline (428.691 us; speedup 1.0000x reference)
//
#include <hip/hip_runtime.h>
#include <math.h>

// EncoderBlock: B=8, N=1024, EMB=768, HEADS=8, DHEAD=96
// R11 = R10 with the m201-faithful sync discipline (the R10 regression was
//       traced to per-phase vmcnt syncs + sched_barrier pinning):
//   - s_waitcnt vmcnt(6) ONCE per K-tile (after P4's MFMAs), not every phase.
//     Gating proof: end-of-tile-t vmcnt(6) leaves only tile-t's P2/P3/P4
//     stages (6 loads) outstanding => all of tile-(t-1)'s stages + t's P1
//     stage have landed = exactly {A0,B1,A1,B0}(t+1). Tail pair drains 0.
//   - no sched_barrier(0) anywhere in the loop (m141 failure mode).
//   - conveyor unchanged: sigma = {P1: B0(t+1), P2: A0(t+2), P3: B1(t+2),
//     P4: A1(t+2)}, liveness-correct slot reuse, 3 half-tiles in flight.
//   Everything else identical to R10 (grids, swizzle, epilogues, FF2 splitK2).

typedef __bf16 bf16_t;
typedef __bf16 bf16x4 __attribute__((ext_vector_type(4)));
typedef __bf16 bf16x8 __attribute__((ext_vector_type(8)));
typedef float f32x4 __attribute__((ext_vector_type(4)));

#define EMB   768
#define HEADS 8
#define DHEAD 96
#define BATCH 8
#define SEQ   1024
#define ROWS  (BATCH * SEQ)   // 8192

__device__ __forceinline__ void load16_lds(const bf16_t* g, bf16_t* l) {
    __builtin_amdgcn_global_load_lds(
        (__attribute__((address_space(1))) unsigned int*)g,
        (__attribute__((address_space(3))) unsigned int*)l,
        16, 0, 0);
}

// ---------------------------------------------------------------- conversions

__global__ void cvt_bf16_kernel(const float* __restrict__ in, bf16_t* __restrict__ out, int n) {
    int stride = gridDim.x * blockDim.x;
    for (int i = blockIdx.x * blockDim.x + threadIdx.x; i < n; i += stride)
        out[i] = (bf16_t)in[i];
}

// in: [K][N] fp32 row-major  ->  out: [N][K] bf16 row-major (B^T for GEMMs)
__global__ void transpose_cvt_kernel(const float* __restrict__ in, bf16_t* __restrict__ out,
                                     int K, int N) {
    __shared__ float t[32][33];
    int n0 = blockIdx.x * 32, k0 = blockIdx.y * 32;
    int tx = threadIdx.x, ty0 = threadIdx.y;  // block (32,8)
#pragma unroll
    for (int i = 0; i < 4; i++) {
        int ty = ty0 + 8 * i;
        t[ty][tx] = in[(size_t)(k0 + ty) * N + n0 + tx];
    }
    __syncthreads();
#pragma unroll
    for (int i = 0; i < 4; i++) {
        int ty = ty0 + 8 * i;
        out[(size_t)(n0 + ty) * K + k0 + tx] = (bf16_t)t[tx][ty];
    }
}

// w_qkvr [768][3072] -> wqkvrT [3072][768] bf16 with COLUMN PERMUTATION:
// output row n' = which*768 + hd  <-  source column hd*4 + which.
__global__ void qkvr_transpose_kernel(const float* __restrict__ in, bf16_t* __restrict__ out) {
    __shared__ float t[32][33];
    int n0 = blockIdx.x * 32, k0 = blockIdx.y * 32;
    int tx = threadIdx.x, ty0 = threadIdx.y;  // block (32,8)
    const int which = n0 / 768, hd0 = n0 % 768;
#pragma unroll
    for (int i = 0; i < 4; i++) {
        int ty = ty0 + 8 * i;
        t[ty][tx] = in[(size_t)(k0 + ty) * 3072 + (hd0 + tx) * 4 + which];
    }
    __syncthreads();
#pragma unroll
    for (int i = 0; i < 4; i++) {
        int ty = ty0 + 8 * i;
        out[(size_t)(n0 + ty) * 768 + k0 + tx] = (bf16_t)t[tx][ty];
    }
}

// ---------------------------------------------------------------- GEMM 256x256 (bf16 MFMA)
// C[M,N] = A[M,K] @ BT[N,K]^T + bias. 512 thr = 8 waves as 2(M)x4(N);
// wave C = 128x64, quadrants (mh,nh) of 64x32 -> acc[2][4][2][2].
// LDS halves per buffer: A0(rows 0-127), A1(128-255), B0(cols 0-127), B1.
// Read liveness (quadrant order (0,0),(0,1),(1,1),(1,0)):
//   A0 read P1 (held for P2), B1 read P2 (held P3), A1 read P3 (held P4),
//   B0 read P1 and re-read P4. => A0 slot dead after P1-issue epoch, etc.

enum { EPI_QKVR = 0, EPI_PROJ = 1, EPI_GELU = 2, EPI_FF2 = 3 };

#define VMW6 asm volatile("s_waitcnt vmcnt(6)" ::: "memory")
#define VMW0 asm volatile("s_waitcnt vmcnt(0)" ::: "memory")
#define VMNONE do {} while (0)

#define READ_A(MH, ABUF) do { \
    _Pragma("unroll") for (int mi = 0; mi < 4; mi++) { \
        const int R_ = (MH) * 128 + wm * 64 + mi * 16 + col16; \
        _Pragma("unroll") for (int kc = 0; kc < 2; kc++) { \
            af[mi][kc] = *reinterpret_cast<const bf16x8*>( \
                (ABUF) + R_ * 64 + (((kc * 4 + quad) ^ (R_ & 7)) * 8)); \
        } \
    } \
} while (0)

#define READ_B(NH, BBUF) do { \
    _Pragma("unroll") for (int ni = 0; ni < 2; ni++) { \
        const int S_ = (NH) * 128 + wn * 32 + ni * 16 + col16; \
        _Pragma("unroll") for (int kc = 0; kc < 2; kc++) { \
            bfr[ni][kc] = *reinterpret_cast<const bf16x8*>( \
                (BBUF) + S_ * 64 + (((kc * 4 + quad) ^ (S_ & 7)) * 8)); \
        } \
    } \
} while (0)

#define MFMAS(MH, NH) do { \
    __builtin_amdgcn_s_setprio(1); \
    _Pragma("unroll") for (int mi = 0; mi < 4; mi++) { \
        _Pragma("unroll") for (int ni = 0; ni < 2; ni++) { \
            _Pragma("unroll") for (int kc = 0; kc < 2; kc++) { \
                acc[MH][mi][NH][ni] = __builtin_amdgcn_mfma_f32_16x16x32_bf16( \
                    af[mi][kc], bfr[ni][kc], acc[MH][mi][NH][ni], 0, 0, 0); \
            } \
        } \
    } \
    __builtin_amdgcn_s_setprio(0); \
} while (0)

// halves: 0=A0, 1=A1, 2=B0, 3=B1
#define STAGE(h_, t_, pd_) do { \
    bf16_t* db_ = lds + (pd_) * 32768; \
    const bf16_t* sp_ = ((h_) < 2 ? A : BT); \
    load16_lds(sp_ + gof[h_][0] + (size_t)(t_) * 64, db_ + lof[h_][0]); \
    load16_lds(sp_ + gof[h_][1] + (size_t)(t_) * 64, db_ + lof[h_][1]); \
} while (0)

// One K-tile = 4 phases; single VM gate in P4 (post-MFMA, pre-barrier).
#define TILE4(t_, PAR, S1, S234, VM) do { \
    const bf16_t* Ab_ = lds + (PAR) * 32768; \
    const bf16_t* Bb_ = Ab_ + 16384; \
    /* P1: quadrant (0,0) */ \
    READ_A(0, Ab_); READ_B(0, Bb_); \
    if (S1) STAGE(2, (t_) + 1, (PAR) ^ 1); \
    __builtin_amdgcn_s_barrier(); \
    MFMAS(0, 0); \
    __builtin_amdgcn_s_barrier(); \
    /* P2: quadrant (0,1) */ \
    READ_B(1, Bb_); \
    if (S234) STAGE(0, (t_) + 2, PAR); \
    __builtin_amdgcn_s_barrier(); \
    MFMAS(0, 1); \
    __builtin_amdgcn_s_barrier(); \
    /* P3: quadrant (1,1) */ \
    READ_A(1, Ab_); \
    if (S234) STAGE(3, (t_) + 2, PAR); \
    __builtin_amdgcn_s_barrier(); \
    MFMAS(1, 1); \
    __builtin_amdgcn_s_barrier(); \
    /* P4: quadrant (1,0), B0 re-read */ \
    READ_B(0, Bb_); \
    if (S234) STAGE(1, (t_) + 2, PAR); \
    __builtin_amdgcn_s_barrier(); \
    MFMAS(1, 0); \
    VM;  /* once per K-tile: loads landed under the MFMAs above */ \
    __builtin_amdgcn_s_barrier(); \
} while (0)

template <int EPI, int KSTRIDE, int NKT, int NBX, int SPLIT>
__global__ __launch_bounds__(512, 2) void gemm256_kernel(
    const bf16_t* __restrict__ A,    // [M,KSTRIDE]
    const bf16_t* __restrict__ BT,   // [N,KSTRIDE]
    const float* __restrict__ bias,  // [N] (EPI_QKVR: original qkvr order)
    bf16_t* __restrict__ qo, bf16_t* __restrict__ ko,
    bf16_t* __restrict__ vTo, bf16_t* __restrict__ ro,   // EPI_QKVR outputs
    const float* __restrict__ resid,                     // EPI_PROJ / EPI_FF2 residual
    float* __restrict__ outf,                            // EPI_PROJ / EPI_FF2 fp32 out
    bf16_t* __restrict__ outb,                           // EPI_GELU bf16 out
    float* __restrict__ outf2)                           // SPLIT partial out
{
    __shared__ __align__(16) bf16_t lds[2 * 32768];  // 128 KiB: 2 x (A 32K + B 32K elems)

    const int tid  = threadIdx.x;
    const int wave = tid >> 6, lane = tid & 63;
    const int quad = lane >> 4, col16 = lane & 15;
    const int wm = wave >> 2, wn = wave & 3;  // 2(M) x 4(N)

    // bijective XCD swizzle (gridDim.x % 8 == 0 for all launches)
    const int cpx  = gridDim.x >> 3;
    const int id   = blockIdx.x;
    const int wgid = (id & 7) * cpx + (id >> 3);
    int byy = wgid / NBX;
    int split = 0;
    if (SPLIT) { split = byy >> 5; byy &= 31; }
    const int bx = wgid % NBX, by = byy;
    const int m0 = by * 256, n0 = bx * 256;
    if (SPLIT) { A += (size_t)split * (NKT * 64); BT += (size_t)split * (NKT * 64); }

    // staging maps: 16B unit u within a half (1024 units); row r=u>>3,
    // global k-unit j = (u&7)^(r&7) (source pre-swizzle, LDS dst linear).
    size_t gof[4][2];
    int    lof[4][2];
#pragma unroll
    for (int i = 0; i < 2; i++) {
        const int u = tid + i * 512;
        const int r = u >> 3;
        const int j = (u & 7) ^ (r & 7);
#pragma unroll
        for (int h = 0; h < 2; h++) {
            gof[h][i]     = (size_t)(m0 + h * 128 + r) * KSTRIDE + j * 8;
            gof[2 + h][i] = (size_t)(n0 + h * 128 + r) * KSTRIDE + j * 8;
            lof[h][i]     = (h * 1024 + u) * 8;
            lof[2 + h][i] = 16384 + (h * 1024 + u) * 8;
        }
    }

    f32x4 acc[2][4][2][2] = {};
    bf16x8 af[4][2], bfr[2][2];

    // prologue: sigma-order stages for tiles 0,1 (7 stages = 14 loads);
    // vmcnt(6) -> oldest 8 done = all four halves of tile 0.
    STAGE(0, 0, 0); STAGE(3, 0, 0); STAGE(1, 0, 0); STAGE(2, 0, 0);
    STAGE(0, 1, 1); STAGE(3, 1, 1); STAGE(1, 1, 1);
    VMW6; __builtin_amdgcn_s_barrier();

#pragma unroll 1
    for (int tt = 0; tt < NKT / 2 - 1; ++tt) {
        const int t0 = 2 * tt;
        TILE4(t0,     0, 1, 1, VMW6);
        TILE4(t0 + 1, 1, 1, 1, VMW6);
    }
    // tail: stages targeting >= NKT skipped -> drain remaining, then compute.
    TILE4(NKT - 2, 0, 1, 0, VMW0);
    TILE4(NKT - 1, 1, 0, 0, VMNONE);

    // ---------------- epilogues
    // row = m0 + mh*128 + wm*64 + mi*16 + quad*4 + rg
    // col = n0 + nh*128 + wn*32 + ni*16 + col16
    if (EPI == EPI_QKVR) {
        const int whichb = bx / 3;      // BN=256: 3 blocks per 768-col group
        const int hdbase = (bx % 3) * 256;
        if (whichb == 2) {
            // V: transpose store, packed over 4 consecutive seq positions.
#pragma unroll
            for (int mh = 0; mh < 2; mh++)
#pragma unroll
            for (int mi = 0; mi < 4; mi++)
#pragma unroll
            for (int nh = 0; nh < 2; nh++)
#pragma unroll
            for (int ni = 0; ni < 2; ni++) {
                const int hd   = hdbase + nh * 128 + wn * 32 + ni * 16 + col16;
                const int head = hd / DHEAD, dd = hd % DHEAD;
                const float bv = bias[hd * 4 + 2];
                const int row0 = m0 + mh * 128 + wm * 64 + mi * 16 + quad * 4;
                const int b = row0 >> 10, nn0 = row0 & 1023;
                bf16x4 w;
#pragma unroll
                for (int rg = 0; rg < 4; rg++) w[rg] = (bf16_t)(acc[mh][mi][nh][ni][rg] + bv);
                *reinterpret_cast<bf16x4*>(
                    vTo + ((size_t)(b * HEADS + head) * DHEAD + dd) * SEQ + nn0) = w;
            }
        } else {
            bf16_t* dst = (whichb == 0) ? qo : (whichb == 1) ? ko : ro;
#pragma unroll
            for (int mh = 0; mh < 2; mh++)
#pragma unroll
            for (int mi = 0; mi < 4; mi++)
#pragma unroll
            for (int nh = 0; nh < 2; nh++)
#pragma unroll
            for (int ni = 0; ni < 2; ni++) {
                const int hd   = hdbase + nh * 128 + wn * 32 + ni * 16 + col16;
                const int head = hd / DHEAD, dd = hd % DHEAD;
                const float bv = bias[hd * 4 + whichb];
#pragma unroll
                for (int rg = 0; rg < 4; rg++) {
                    const int row = m0 + mh * 128 + wm * 64 + mi * 16 + quad * 4 + rg;
                    const int b = row >> 10, nn = row & 1023;
                    dst[((size_t)(b * HEADS + head) * SEQ + nn) * DHEAD + dd] =
                        (bf16_t)(acc[mh][mi][nh][ni][rg] + bv);
                }
            }
        }
    } else {
        const bool part = (SPLIT != 0) && (split == 1);
#pragma unroll
        for (int mh = 0; mh < 2; mh++)
#pragma unroll
        for (int mi = 0; mi < 4; mi++)
#pragma unroll
        for (int nh = 0; nh < 2; nh++)
#pragma unroll
        for (int ni = 0; ni < 2; ni++) {
            const int colg = n0 + nh * 128 + wn * 32 + ni * 16 + col16;
#pragma unroll
            for (int rg = 0; rg < 4; rg++) {
                const int row = m0 + mh * 128 + wm * 64 + mi * 16 + quad * 4 + rg;
                const float a = acc[mh][mi][nh][ni][rg];
                if (EPI == EPI_GELU) {
                    const float v = a + bias[colg];
                    // tanh-form gelu via sigmoid (|err|<3e-3 vs erf)
                    const float z = 1.5957691216057308f * v * (1.0f + 0.044715f * v * v);
                    const float g = v / (1.0f + __expf(-z));
                    outb[(size_t)row * 3072 + colg] = (bf16_t)g;
                } else if (part) {
                    outf2[(size_t)row * EMB + colg] = a;  // raw partial, no bias
                } else {
                    outf[(size_t)row * EMB + colg] =
                        a + bias[colg] + resid[(size_t)row * EMB + colg];
                }
            }
        }
    }
}

// ---------------------------------------------------------------- attention
// (unchanged)

__global__ __launch_bounds__(256) void attn_kernel(
    const bf16_t* __restrict__ q, const bf16_t* __restrict__ k,
    const bf16_t* __restrict__ vT, const bf16_t* __restrict__ r,
    bf16_t* __restrict__ attn_out)
{
    __shared__ __align__(16) bf16_t Ks[64 * 96];    // [key][dim]
    __shared__ __align__(16) bf16_t Vs[96 * 64];    // [feat][16B-unit swizzled by feat&7]
    __shared__ __align__(16) bf16_t P[4][16 * 72];  // wave-private P (barriers protect reuse)

    const int tid = threadIdx.x, wave = tid >> 6, lane = tid & 63;
    const int quad = lane >> 4, col = lane & 15;
    const int bh = blockIdx.x & 63, qb = blockIdx.x >> 6;
    const int n0 = qb * 64 + wave * 16;
    const bf16_t* qp = q  + (size_t)bh * SEQ * DHEAD;
    const bf16_t* kb = k  + (size_t)bh * SEQ * DHEAD;
    const bf16_t* vb = vT + (size_t)bh * DHEAD * SEQ;
    bf16_t* Pw = P[wave];

    bf16x8 qf[3];  // Q as B-operand: B[k=dim][n=q-row]
#pragma unroll
    for (int ks = 0; ks < 3; ks++)
        qf[ks] = *reinterpret_cast<const bf16x8*>(qp + (size_t)(n0 + col) * DHEAD + ks * 32 + quad * 8);

    // staging unit ids (16B units): K has 64*12=768, V has 96*8=768
    const int u0 = tid, u1 = tid + 256, u2 = tid + 512;
    const int vf0 = u0 >> 3, vp0 = (u0 & 7) ^ (vf0 & 7);
    const int vf1 = u1 >> 3, vp1 = (u1 & 7) ^ (vf1 & 7);
    const int vf2 = u2 >> 3, vp2 = (u2 & 7) ^ (vf2 & 7);

    f32x4 O[6] = {};
    float lsum = 0.f;  // per-lane partial row-sum for q-row `col`

    for (int ch = 0; ch < SEQ / 64; ch++) {
        const int kc0 = ch * 64;
        __syncthreads();  // all waves done reading Ks/Vs of previous chunk
        const bf16_t* ksrc = kb + (size_t)kc0 * DHEAD;  // 64 keys x 96 dims, contiguous
        load16_lds(ksrc + u0 * 8, Ks + u0 * 8);
        load16_lds(ksrc + u1 * 8, Ks + u1 * 8);
        load16_lds(ksrc + u2 * 8, Ks + u2 * 8);
        load16_lds(vb + (size_t)vf0 * SEQ + kc0 + vp0 * 8, Vs + u0 * 8);
        load16_lds(vb + (size_t)vf1 * SEQ + kc0 + vp1 * 8, Vs + u1 * 8);
        load16_lds(vb + (size_t)vf2 * SEQ + kc0 + vp2 * 8, Vs + u2 * 8);
        __syncthreads();  // compiler drains vmcnt before barrier: tiles ready

        f32x4 s[4] = {};
#pragma unroll
        for (int ks = 0; ks < 3; ks++) {  // K as A-operand: A[m=key][k=dim]
#pragma unroll
            for (int h = 0; h < 4; h++) {
                bf16x8 kf = *reinterpret_cast<const bf16x8*>(Ks + (h * 16 + col) * DHEAD + ks * 32 + quad * 8);
                s[h] = __builtin_amdgcn_mfma_f32_16x16x32_bf16(kf, qf[ks], s[h], 0, 0, 0);
            }
        }
        // S^T C-layout: lane holds keys h*16+quad*4+rg for q-row `col`
#pragma unroll
        for (int h = 0; h < 4; h++) {
            bf16x4 w;
#pragma unroll
            for (int rg = 0; rg < 4; rg++) {
                const float e = __expf(s[h][rg]);
                lsum += e;
                w[rg] = (bf16_t)e;
            }
            *reinterpret_cast<bf16x4*>(Pw + col * 72 + h * 16 + quad * 4) = w;
        }
        // A-operand read back: A[m=q-row=col][k=key]
        bf16x8 af0 = *reinterpret_cast<const bf16x8*>(Pw + col * 72 + quad * 8);
        bf16x8 af1 = *reinterpret_cast<const bf16x8*>(Pw + col * 72 + 32 + quad * 8);
#pragma unroll
        for (int tc = 0; tc < 6; tc++) {  // V as B-operand: B[k=key][n=feat]
            const int feat = tc * 16 + col;
            bf16x8 bv0 = *reinterpret_cast<const bf16x8*>(Vs + feat * 64 + ((quad)     ^ (col & 7)) * 8);
            bf16x8 bv1 = *reinterpret_cast<const bf16x8*>(Vs + feat * 64 + ((4 + quad) ^ (col & 7)) * 8);
            O[tc] = __builtin_amdgcn_mfma_f32_16x16x32_bf16(af0, bv0, O[tc], 0, 0, 0);
            O[tc] = __builtin_amdgcn_mfma_f32_16x16x32_bf16(af1, bv1, O[tc], 0, 0, 0);
        }
    }

    // finalize row sums: reduce over quads (lanes sharing `col`)
    lsum += __shfl_xor(lsum, 16);
    lsum += __shfl_xor(lsum, 32);

    const float inv_sqrt_emb = 0.036084391824351615f;  // 1/sqrt(768)
    const int b = bh >> 3, h = bh & 7;
#pragma unroll
    for (int rg = 0; rg < 4; rg++) {
        const int nrow = quad * 4 + rg;
        const float lr = __shfl(lsum, nrow);  // lane nrow holds q-row nrow's sum
        const float scale = inv_sqrt_emb / lr;
        const int n = n0 + nrow;
#pragma unroll
        for (int tc = 0; tc < 6; tc++) {
            const int feat = tc * 16 + col;
            const float rv = (float)r[((size_t)bh * SEQ + n) * DHEAD + feat];
            attn_out[((size_t)(b * SEQ + n)) * EMB + h * DHEAD + feat] = (bf16_t)(O[tc][rg] * scale * rv);
        }
    }
}

// ---------------------------------------------------------------- LayerNorm (row=768)
// in2 != nullptr: normalize (in + in2) (FF2 split-K partial sum)

__global__ __launch_bounds__(256) void ln_kernel(
    const float* __restrict__ in, const float* __restrict__ in2,
    const float* __restrict__ g, const float* __restrict__ b,
    float* __restrict__ y, bf16_t* __restrict__ yb)
{
    const int row = blockIdx.x * 4 + (threadIdx.x >> 6);
    const int lane = threadIdx.x & 63;
    const float* rp = in + (size_t)row * EMB;
    const float* rp2 = in2 ? in2 + (size_t)row * EMB : nullptr;
    float v[12];
    float sum = 0.f;
#pragma unroll
    for (int i = 0; i < 12; i++) {
        v[i] = rp[lane + i * 64];
        if (in2) v[i] += rp2[lane + i * 64];
        sum += v[i];
    }
#pragma unroll
    for (int off = 32; off; off >>= 1) sum += __shfl_xor(sum, off);
    const float mean = sum * (1.0f / 768.0f);
    float s2 = 0.f;
#pragma unroll
    for (int i = 0; i < 12; i++) { float d = v[i] - mean; s2 += d * d; }
#pragma unroll
    for (int off = 32; off; off >>= 1) s2 += __shfl_xor(s2, off);
    const float inv = rsqrtf(s2 * (1.0f / 768.0f) + 1e-5f);
#pragma unroll
    for (int i = 0; i < 12; i++) {
        const int c = lane + i * 64;
        const float o = (v[i] - mean) * inv * g[c] + b[c];
        y[(size_t)row * EMB + c] = o;
        if (yb) yb[(size_t)row * EMB + c] = (bf16_t)o;
    }
}

// ---------------------------------------------------------------- launch

extern "C" void kernel_launch(void* const* d_in, const int* in_sizes, int n_in,
                              void* d_out, int out_size, void* d_ws, size_t ws_size,
                              hipStream_t stream)
{
    const float* x      = (const float*)d_in[0];
    const float* w_qkvr = (const float*)d_in[1];
    const float* b_qkvr = (const float*)d_in[2];
    const float* w_proj = (const float*)d_in[3];
    const float* b_proj = (const float*)d_in[4];
    const float* ln1_g  = (const float*)d_in[5];
    const float* ln1_b  = (const float*)d_in[6];
    const float* w_ff1  = (const float*)d_in[7];
    const float* b_ff1  = (const float*)d_in[8];
    const float* w_ff2  = (const float*)d_in[9];
    const float* b_ff2  = (const float*)d_in[10];
    const float* ln2_g  = (const float*)d_in[11];
    const float* ln2_b  = (const float*)d_in[12];
    float* out = (float*)d_out;

    char* ws = (char*)d_ws;
    size_t off = 0;
    auto alloc = [&](size_t bytes) {
        char* p = ws + off;
        off += (bytes + 255) & ~(size_t)255;
        return (void*)p;
    };
    const size_t ACT = (size_t)ROWS * EMB;  // 6291456
    bf16_t* xb      = (bf16_t*)alloc(ACT * 2);
    bf16_t* wqkvrT  = (bf16_t*)alloc((size_t)3072 * 768 * 2);
    bf16_t* wprojT  = (bf16_t*)alloc((size_t)768 * 768 * 2);
    bf16_t* wff1T   = (bf16_t*)alloc((size_t)3072 * 768 * 2);
    bf16_t* wff2T   = (bf16_t*)alloc((size_t)768 * 3072 * 2);
    bf16_t* qbuf    = (bf16_t*)alloc(ACT * 2);
    bf16_t* kbuf    = (bf16_t*)alloc(ACT * 2);
    bf16_t* vTbuf   = (bf16_t*)alloc(ACT * 2);
    bf16_t* rbuf    = (bf16_t*)alloc(ACT * 2);
    bf16_t* attn_o  = (bf16_t*)alloc(ACT * 2);
    float*  x1f     = (float*)alloc(ACT * 4);
    bf16_t* x1b     = (bf16_t*)alloc(ACT * 2);
    bf16_t* ff1     = (bf16_t*)alloc((size_t)ROWS * 3072 * 2);
    float*  res     = out;              // d_out doubles as fp32 residual scratch
    float*  res2    = (float*)qbuf;     // FF2 split-1 partial; q/k dead by then (25 MB)

    dim3 tb32(32, 8);

    cvt_bf16_kernel<<<2048, 256, 0, stream>>>(x, xb, (int)ACT);
    qkvr_transpose_kernel<<<dim3(3072 / 32, 768 / 32), tb32, 0, stream>>>(w_qkvr, wqkvrT);
    transpose_cvt_kernel<<<dim3(768 / 32, 768 / 32), tb32, 0, stream>>>(w_proj, wprojT, 768, 768);
    transpose_cvt_kernel<<<dim3(3072 / 32, 768 / 32), tb32, 0, stream>>>(w_ff1, wff1T, 768, 3072);
    transpose_cvt_kernel<<<dim3(768 / 32, 3072 / 32), tb32, 0, stream>>>(w_ff2, wff2T, 3072, 768);

    // QKVR: M=8192, N=3072 -> 32 x 12 = 384 blocks
    gemm256_kernel<EPI_QKVR, 768, 12, 12, 0><<<384, 512, 0, stream>>>(
        xb, wqkvrT, b_qkvr, qbuf, kbuf, vTbuf, rbuf, nullptr, nullptr, nullptr, nullptr);

    attn_kernel<<<dim3(SEQ / 64 * BATCH * HEADS), 256, 0, stream>>>(qbuf, kbuf, vTbuf, rbuf, attn_o);

    // PROJ: M=8192, N=768 -> 32 x 3 = 96 blocks
    gemm256_kernel<EPI_PROJ, 768, 12, 3, 0><<<96, 512, 0, stream>>>(
        attn_o, wprojT, b_proj, nullptr, nullptr, nullptr, nullptr, x, res, nullptr, nullptr);
    ln_kernel<<<2048, 256, 0, stream>>>(res, nullptr, ln1_g, ln1_b, x1f, x1b);

    // FF1+GELU: M=8192, N=3072
    gemm256_kernel<EPI_GELU, 768, 12, 12, 0><<<384, 512, 0, stream>>>(
        x1b, wff1T, b_ff1, nullptr, nullptr, nullptr, nullptr, nullptr, nullptr, ff1, nullptr);

    // FF2: M=8192, N=768, K=3072, split-K x2 (192 co-resident blocks)
    gemm256_kernel<EPI_FF2, 3072, 24, 3, 1><<<192, 512, 0, stream>>>(
        ff1, wff2T, b_ff2, nullptr, nullptr, nullptr, nullptr, x1f, res, nullptr, res2);
    ln_kernel<<<2048, 256, 0, stream>>>(res, res2, ln2_g, ln2_b, out, nullptr);

    (void)in_sizes; (void)n_in; (void)out_size; (void)ws_size;
}

// Round 4
// 384.512 us; speedup vs baseline: 1.1149x; 1.1149x over previous
//
#include <hip/hip_runtime.h>
#include <math.h>

// EncoderBlock: B=8, N=1024, EMB=768, HEADS=8, DHEAD=96
// R12: single-barrier never-drain GEMM K-loop (R9 triple-buffer geometry).
//   Cross-round data: R8/R9/R10/R11 all plateau at 16-17 cy/MFMA-instr/CU.
//   Two removable costs identified: (a) R9 rematerializes swizzled LDS read
//   addresses every phase (VALUBusy 35% > MfmaUtil); (b) barrier between
//   ds_read window and MFMA window forces strict alternation of LDS and
//   MFMA pipes. Triple buffering makes that barrier unnecessary:
//   stage target of tile t = buf((t+2)%3) was last read at tile t-1 and all
//   reads complete before t-1's end barrier (lgkm before MFMA before bar).
//   So: per K-tile = {ds_read x16 (precomputed offsets) | stage 6 loads |
//   32 MFMA | vmcnt(6) | sched_barrier(0); s_barrier}. One barrier, one
//   counted wait per tile; drain only in the 2-tile tail.
//   Grids / epilogues / swizzle / attn / LN verbatim from R9 (best: 381.7us).

typedef __bf16 bf16_t;
typedef __bf16 bf16x4 __attribute__((ext_vector_type(4)));
typedef __bf16 bf16x8 __attribute__((ext_vector_type(8)));
typedef float f32x4 __attribute__((ext_vector_type(4)));

#define EMB   768
#define HEADS 8
#define DHEAD 96
#define BATCH 8
#define SEQ   1024
#define ROWS  (BATCH * SEQ)   // 8192

__device__ __forceinline__ void load16_lds(const bf16_t* g, bf16_t* l) {
    __builtin_amdgcn_global_load_lds(
        (__attribute__((address_space(1))) unsigned int*)g,
        (__attribute__((address_space(3))) unsigned int*)l,
        16, 0, 0);
}

// ---------------------------------------------------------------- conversions

__global__ void cvt_bf16_kernel(const float* __restrict__ in, bf16_t* __restrict__ out, int n) {
    int stride = gridDim.x * blockDim.x;
    for (int i = blockIdx.x * blockDim.x + threadIdx.x; i < n; i += stride)
        out[i] = (bf16_t)in[i];
}

// in: [K][N] fp32 row-major  ->  out: [N][K] bf16 row-major (B^T for GEMMs)
__global__ void transpose_cvt_kernel(const float* __restrict__ in, bf16_t* __restrict__ out,
                                     int K, int N) {
    __shared__ float t[32][33];
    int n0 = blockIdx.x * 32, k0 = blockIdx.y * 32;
    int tx = threadIdx.x, ty0 = threadIdx.y;  // block (32,8)
#pragma unroll
    for (int i = 0; i < 4; i++) {
        int ty = ty0 + 8 * i;
        t[ty][tx] = in[(size_t)(k0 + ty) * N + n0 + tx];
    }
    __syncthreads();
#pragma unroll
    for (int i = 0; i < 4; i++) {
        int ty = ty0 + 8 * i;
        out[(size_t)(n0 + ty) * K + k0 + tx] = (bf16_t)t[tx][ty];
    }
}

// w_qkvr [768][3072] -> wqkvrT [3072][768] bf16 with COLUMN PERMUTATION:
// output row n' = which*768 + hd  <-  source column hd*4 + which.
__global__ void qkvr_transpose_kernel(const float* __restrict__ in, bf16_t* __restrict__ out) {
    __shared__ float t[32][33];
    int n0 = blockIdx.x * 32, k0 = blockIdx.y * 32;
    int tx = threadIdx.x, ty0 = threadIdx.y;  // block (32,8)
    const int which = n0 / 768, hd0 = n0 % 768;
#pragma unroll
    for (int i = 0; i < 4; i++) {
        int ty = ty0 + 8 * i;
        t[ty][tx] = in[(size_t)(k0 + ty) * 3072 + (hd0 + tx) * 4 + which];
    }
    __syncthreads();
#pragma unroll
    for (int i = 0; i < 4; i++) {
        int ty = ty0 + 8 * i;
        out[(size_t)(n0 + ty) * 768 + k0 + tx] = (bf16_t)t[tx][ty];
    }
}

// ---------------------------------------------------------------- GEMM (bf16 MFMA)
// C[M,N] = A[M,K] @ BT[N,K]^T + bias. Tile 256(M)x128(N), BK=64, 512 thr =
// 8 waves as 4(M)x2(N); wave C = 64x64 -> acc[4][4] of 16x16 frags.
// LDS: 3 buffers x (A 32KB + B 16KB) = 144 KiB -> 1 block/CU, 2 waves/SIMD.

enum { EPI_QKVR = 0, EPI_PROJ = 1, EPI_GELU = 2, EPI_FF2 = 3 };

#define VMW6 asm volatile("s_waitcnt vmcnt(6)" ::: "memory")
#define VMW0 asm volatile("s_waitcnt vmcnt(0)" ::: "memory")
#define VMNONE do {} while (0)

// 8 ds_read_b128 for one kc from precomputed byte offsets
#define RD8(KC, LB) do { \
    _Pragma("unroll") for (int u = 0; u < 4; u++) { \
        af[u]  = *reinterpret_cast<const bf16x8*>((LB) + aoff[KC][u]); \
        bfr[u] = *reinterpret_cast<const bf16x8*>((LB) + boff[KC][u]); \
    } \
} while (0)

#define MM16() do { \
    __builtin_amdgcn_s_setprio(1); \
    _Pragma("unroll") for (int tr = 0; tr < 4; tr++) \
        _Pragma("unroll") for (int tc = 0; tc < 4; tc++) \
            acc[tr][tc] = __builtin_amdgcn_mfma_f32_16x16x32_bf16( \
                af[tr], bfr[tc], acc[tr][tc], 0, 0, 0); \
    __builtin_amdgcn_s_setprio(0); \
} while (0)

// stage one K-tile (6 loads) into buffer DB; running pointers advance
#define STAGE6(DB) do { \
    bf16_t* db_ = lds + (DB) * 24576; \
    _Pragma("unroll") for (int i2 = 0; i2 < 4; i2++) { load16_lds(pa[i2], db_ + lA[i2]); pa[i2] += 64; } \
    _Pragma("unroll") for (int i2 = 0; i2 < 2; i2++) { load16_lds(pb[i2], db_ + lB[i2]); pb[i2] += 64; } \
} while (0)

// One K-tile: reads+stage+MFMAs in ONE inter-barrier window.
#define TILE1(BUF, DOSTAGE, GATE, DOBAR) do { \
    const char* lb_ = (const char*)lds + (BUF) * 49152; \
    bf16x8 af[4], bfr[4]; \
    RD8(0, lb_); \
    if (DOSTAGE) STAGE6(((BUF) + 2) % 3); \
    MM16(); \
    RD8(1, lb_); \
    MM16(); \
    GATE; \
    if (DOBAR) { __builtin_amdgcn_sched_barrier(0); __builtin_amdgcn_s_barrier(); } \
} while (0)

template <int EPI, int KSTRIDE, int NKT, int NBX>
__global__ __launch_bounds__(512, 2) void gemmsb_kernel(
    const bf16_t* __restrict__ A,    // [M,KSTRIDE]
    const bf16_t* __restrict__ BT,   // [N,KSTRIDE]
    const float* __restrict__ bias,  // [N] (EPI_QKVR: original qkvr order)
    bf16_t* __restrict__ qo, bf16_t* __restrict__ ko,
    bf16_t* __restrict__ vTo, bf16_t* __restrict__ ro,   // EPI_QKVR outputs
    const float* __restrict__ resid,                     // EPI_PROJ / EPI_FF2 residual
    float* __restrict__ outf,                            // EPI_PROJ / EPI_FF2 fp32 out
    bf16_t* __restrict__ outb)                           // EPI_GELU bf16 out
{
    __shared__ __align__(16) bf16_t lds[3 * 24576];  // 144 KiB

    const int tid  = threadIdx.x;
    const int wave = tid >> 6, lane = tid & 63;
    const int quad = lane >> 4, col16 = lane & 15;
    const int wrow = (wave >> 1) * 64, wcol = (wave & 1) * 64;  // 4(M) x 2(N)

    // bijective XCD swizzle (gridDim.x % 8 == 0 for all launches)
    const int cpx  = gridDim.x >> 3;
    const int id   = blockIdx.x;
    const int wgid = (id & 7) * cpx + (id >> 3);
    const int bx = wgid % NBX, by = wgid / NBX;
    const int m0 = by * 256, n0 = bx * 128;

    // -------- precomputed LDS read byte-offsets (loop-invariant; ~16 VGPR)
    int aoff[2][4], boff[2][4];
#pragma unroll
    for (int kc = 0; kc < 2; kc++) {
#pragma unroll
        for (int u = 0; u < 4; u++) {
            const int R = wrow + u * 16 + col16;          // A row 0..255
            aoff[kc][u] = R * 128 + (((kc * 4 + quad) ^ (R & 7)) * 16);
            const int S = wcol + u * 16 + col16;          // B row 0..127
            boff[kc][u] = 32768 + S * 128 + (((kc * 4 + quad) ^ (S & 7)) * 16);
        }
    }

    // -------- staging maps (A: 2048 16B units, B: 1024), source pre-swizzled
    const bf16_t* pa[4]; const bf16_t* pb[2];
    int lA[4], lB[2];
#pragma unroll
    for (int i = 0; i < 4; i++) {
        const int u = tid + 512 * i;
        const int r = u >> 3, j = (u & 7) ^ (r & 7);
        pa[i] = A + (size_t)(m0 + r) * KSTRIDE + j * 8;
        lA[i] = u * 8;
    }
#pragma unroll
    for (int i = 0; i < 2; i++) {
        const int u = tid + 512 * i;
        const int r = u >> 3, j = (u & 7) ^ (r & 7);
        pb[i] = BT + (size_t)(n0 + r) * KSTRIDE + j * 8;
        lB[i] = 16384 + u * 8;
    }

    f32x4 acc[4][4] = {};

    // prologue: tiles 0,1 staged; gate tile 0 (12 in flight -> wait <=6)
    STAGE6(0); STAGE6(1);
    VMW6; __builtin_amdgcn_s_barrier();

#pragma unroll 1
    for (int tg = 0; tg < NKT / 3 - 1; ++tg) {
        TILE1(0, 1, VMW6, 1);
        TILE1(1, 1, VMW6, 1);
        TILE1(2, 1, VMW6, 1);
    }
    // tail (tiles NKT-3, NKT-2, NKT-1; NKT % 3 == 0)
    TILE1(0, 1, VMW6, 1);    // stages tile NKT-1
    TILE1(1, 0, VMW0, 1);    // drain: NKT-1's loads must land
    TILE1(2, 0, VMNONE, 0);  // last tile, no sync needed after

    // ---------------- epilogues (verbatim R9)
    // row = m0 + wrow + tr*16 + quad*4 + rg ; col = n0 + wcol + tc*16 + col16
    if (EPI == EPI_QKVR) {
        const int whichb = bx / 6;
        if (whichb == 2) {
            // V: transpose store, packed over 4 consecutive seq positions.
#pragma unroll
            for (int tr = 0; tr < 4; tr++) {
#pragma unroll
                for (int tc = 0; tc < 4; tc++) {
                    const int hd   = (bx % 6) * 128 + wcol + tc * 16 + col16;
                    const int head = hd / DHEAD, dd = hd % DHEAD;
                    const float bv = bias[hd * 4 + 2];
                    const int row0 = m0 + wrow + tr * 16 + quad * 4;
                    const int b = row0 >> 10, nn0 = row0 & 1023;
                    bf16x4 w;
#pragma unroll
                    for (int rg = 0; rg < 4; rg++) w[rg] = (bf16_t)(acc[tr][tc][rg] + bv);
                    *reinterpret_cast<bf16x4*>(
                        vTo + ((size_t)(b * HEADS + head) * DHEAD + dd) * SEQ + nn0) = w;
                }
            }
        } else {
            bf16_t* dst = (whichb == 0) ? qo : (whichb == 1) ? ko : ro;
#pragma unroll
            for (int tr = 0; tr < 4; tr++) {
#pragma unroll
                for (int tc = 0; tc < 4; tc++) {
                    const int hd   = (bx % 6) * 128 + wcol + tc * 16 + col16;
                    const int head = hd / DHEAD, dd = hd % DHEAD;
                    const float bv = bias[hd * 4 + whichb];
#pragma unroll
                    for (int rg = 0; rg < 4; rg++) {
                        const int row = m0 + wrow + tr * 16 + quad * 4 + rg;
                        const int b = row >> 10, nn = row & 1023;
                        dst[((size_t)(b * HEADS + head) * SEQ + nn) * DHEAD + dd] =
                            (bf16_t)(acc[tr][tc][rg] + bv);
                    }
                }
            }
        }
    } else {
#pragma unroll
        for (int tr = 0; tr < 4; tr++) {
#pragma unroll
            for (int tc = 0; tc < 4; tc++) {
#pragma unroll
                for (int rg = 0; rg < 4; rg++) {
                    const int row  = m0 + wrow + tr * 16 + quad * 4 + rg;
                    const int colg = n0 + wcol + tc * 16 + col16;
                    float v = acc[tr][tc][rg] + bias[colg];
                    if (EPI == EPI_PROJ || EPI == EPI_FF2) {
                        outf[(size_t)row * EMB + colg] = v + resid[(size_t)row * EMB + colg];
                    } else {  // EPI_GELU: tanh-form gelu via sigmoid (|err|<3e-3 vs erf)
                        const float z = 1.5957691216057308f * v * (1.0f + 0.044715f * v * v);
                        const float g = v / (1.0f + __expf(-z));
                        outb[(size_t)row * 3072 + colg] = (bf16_t)g;
                    }
                }
            }
        }
    }
}

// ---------------------------------------------------------------- attention
// (unchanged)

__global__ __launch_bounds__(256) void attn_kernel(
    const bf16_t* __restrict__ q, const bf16_t* __restrict__ k,
    const bf16_t* __restrict__ vT, const bf16_t* __restrict__ r,
    bf16_t* __restrict__ attn_out)
{
    __shared__ __align__(16) bf16_t Ks[64 * 96];    // [key][dim]
    __shared__ __align__(16) bf16_t Vs[96 * 64];    // [feat][16B-unit swizzled by feat&7]
    __shared__ __align__(16) bf16_t P[4][16 * 72];  // wave-private P (barriers protect reuse)

    const int tid = threadIdx.x, wave = tid >> 6, lane = tid & 63;
    const int quad = lane >> 4, col = lane & 15;
    const int bh = blockIdx.x & 63, qb = blockIdx.x >> 6;
    const int n0 = qb * 64 + wave * 16;
    const bf16_t* qp = q  + (size_t)bh * SEQ * DHEAD;
    const bf16_t* kb = k  + (size_t)bh * SEQ * DHEAD;
    const bf16_t* vb = vT + (size_t)bh * DHEAD * SEQ;
    bf16_t* Pw = P[wave];

    bf16x8 qf[3];  // Q as B-operand: B[k=dim][n=q-row]
#pragma unroll
    for (int ks = 0; ks < 3; ks++)
        qf[ks] = *reinterpret_cast<const bf16x8*>(qp + (size_t)(n0 + col) * DHEAD + ks * 32 + quad * 8);

    // staging unit ids (16B units): K has 64*12=768, V has 96*8=768
    const int u0 = tid, u1 = tid + 256, u2 = tid + 512;
    const int vf0 = u0 >> 3, vp0 = (u0 & 7) ^ (vf0 & 7);
    const int vf1 = u1 >> 3, vp1 = (u1 & 7) ^ (vf1 & 7);
    const int vf2 = u2 >> 3, vp2 = (u2 & 7) ^ (vf2 & 7);

    f32x4 O[6] = {};
    float lsum = 0.f;  // per-lane partial row-sum for q-row `col`

    for (int ch = 0; ch < SEQ / 64; ch++) {
        const int kc0 = ch * 64;
        __syncthreads();  // all waves done reading Ks/Vs of previous chunk
        const bf16_t* ksrc = kb + (size_t)kc0 * DHEAD;  // 64 keys x 96 dims, contiguous
        load16_lds(ksrc + u0 * 8, Ks + u0 * 8);
        load16_lds(ksrc + u1 * 8, Ks + u1 * 8);
        load16_lds(ksrc + u2 * 8, Ks + u2 * 8);
        load16_lds(vb + (size_t)vf0 * SEQ + kc0 + vp0 * 8, Vs + u0 * 8);
        load16_lds(vb + (size_t)vf1 * SEQ + kc0 + vp1 * 8, Vs + u1 * 8);
        load16_lds(vb + (size_t)vf2 * SEQ + kc0 + vp2 * 8, Vs + u2 * 8);
        __syncthreads();  // compiler drains vmcnt before barrier: tiles ready

        f32x4 s[4] = {};
#pragma unroll
        for (int ks = 0; ks < 3; ks++) {  // K as A-operand: A[m=key][k=dim]
#pragma unroll
            for (int h = 0; h < 4; h++) {
                bf16x8 kf = *reinterpret_cast<const bf16x8*>(Ks + (h * 16 + col) * DHEAD + ks * 32 + quad * 8);
                s[h] = __builtin_amdgcn_mfma_f32_16x16x32_bf16(kf, qf[ks], s[h], 0, 0, 0);
            }
        }
        // S^T C-layout: lane holds keys h*16+quad*4+rg for q-row `col`
#pragma unroll
        for (int h = 0; h < 4; h++) {
            bf16x4 w;
#pragma unroll
            for (int rg = 0; rg < 4; rg++) {
                const float e = __expf(s[h][rg]);
                lsum += e;
                w[rg] = (bf16_t)e;
            }
            *reinterpret_cast<bf16x4*>(Pw + col * 72 + h * 16 + quad * 4) = w;
        }
        // A-operand read back: A[m=q-row=col][k=key]
        bf16x8 af0 = *reinterpret_cast<const bf16x8*>(Pw + col * 72 + quad * 8);
        bf16x8 af1 = *reinterpret_cast<const bf16x8*>(Pw + col * 72 + 32 + quad * 8);
#pragma unroll
        for (int tc = 0; tc < 6; tc++) {  // V as B-operand: B[k=key][n=feat]
            const int feat = tc * 16 + col;
            bf16x8 bv0 = *reinterpret_cast<const bf16x8*>(Vs + feat * 64 + ((quad)     ^ (col & 7)) * 8);
            bf16x8 bv1 = *reinterpret_cast<const bf16x8*>(Vs + feat * 64 + ((4 + quad) ^ (col & 7)) * 8);
            O[tc] = __builtin_amdgcn_mfma_f32_16x16x32_bf16(af0, bv0, O[tc], 0, 0, 0);
            O[tc] = __builtin_amdgcn_mfma_f32_16x16x32_bf16(af1, bv1, O[tc], 0, 0, 0);
        }
    }

    // finalize row sums: reduce over quads (lanes sharing `col`)
    lsum += __shfl_xor(lsum, 16);
    lsum += __shfl_xor(lsum, 32);

    const float inv_sqrt_emb = 0.036084391824351615f;  // 1/sqrt(768)
    const int b = bh >> 3, h = bh & 7;
#pragma unroll
    for (int rg = 0; rg < 4; rg++) {
        const int nrow = quad * 4 + rg;
        const float lr = __shfl(lsum, nrow);  // lane nrow holds q-row nrow's sum
        const float scale = inv_sqrt_emb / lr;
        const int n = n0 + nrow;
#pragma unroll
        for (int tc = 0; tc < 6; tc++) {
            const int feat = tc * 16 + col;
            const float rv = (float)r[((size_t)bh * SEQ + n) * DHEAD + feat];
            attn_out[((size_t)(b * SEQ + n)) * EMB + h * DHEAD + feat] = (bf16_t)(O[tc][rg] * scale * rv);
        }
    }
}

// ---------------------------------------------------------------- LayerNorm (row=768)

__global__ __launch_bounds__(256) void ln_kernel(
    const float* __restrict__ in, const float* __restrict__ g, const float* __restrict__ b,
    float* __restrict__ y, bf16_t* __restrict__ yb)
{
    const int row = blockIdx.x * 4 + (threadIdx.x >> 6);
    const int lane = threadIdx.x & 63;
    const float* rp = in + (size_t)row * EMB;
    float v[12];
    float sum = 0.f;
#pragma unroll
    for (int i = 0; i < 12; i++) { v[i] = rp[lane + i * 64]; sum += v[i]; }
#pragma unroll
    for (int off = 32; off; off >>= 1) sum += __shfl_xor(sum, off);
    const float mean = sum * (1.0f / 768.0f);
    float s2 = 0.f;
#pragma unroll
    for (int i = 0; i < 12; i++) { float d = v[i] - mean; s2 += d * d; }
#pragma unroll
    for (int off = 32; off; off >>= 1) s2 += __shfl_xor(s2, off);
    const float inv = rsqrtf(s2 * (1.0f / 768.0f) + 1e-5f);
#pragma unroll
    for (int i = 0; i < 12; i++) {
        const int c = lane + i * 64;
        const float o = (v[i] - mean) * inv * g[c] + b[c];
        y[(size_t)row * EMB + c] = o;
        if (yb) yb[(size_t)row * EMB + c] = (bf16_t)o;
    }
}

// ---------------------------------------------------------------- launch

extern "C" void kernel_launch(void* const* d_in, const int* in_sizes, int n_in,
                              void* d_out, int out_size, void* d_ws, size_t ws_size,
                              hipStream_t stream)
{
    const float* x      = (const float*)d_in[0];
    const float* w_qkvr = (const float*)d_in[1];
    const float* b_qkvr = (const float*)d_in[2];
    const float* w_proj = (const float*)d_in[3];
    const float* b_proj = (const float*)d_in[4];
    const float* ln1_g  = (const float*)d_in[5];
    const float* ln1_b  = (const float*)d_in[6];
    const float* w_ff1  = (const float*)d_in[7];
    const float* b_ff1  = (const float*)d_in[8];
    const float* w_ff2  = (const float*)d_in[9];
    const float* b_ff2  = (const float*)d_in[10];
    const float* ln2_g  = (const float*)d_in[11];
    const float* ln2_b  = (const float*)d_in[12];
    float* out = (float*)d_out;

    char* ws = (char*)d_ws;
    size_t off = 0;
    auto alloc = [&](size_t bytes) {
        char* p = ws + off;
        off += (bytes + 255) & ~(size_t)255;
        return (void*)p;
    };
    const size_t ACT = (size_t)ROWS * EMB;  // 6291456
    bf16_t* xb      = (bf16_t*)alloc(ACT * 2);
    bf16_t* wqkvrT  = (bf16_t*)alloc((size_t)3072 * 768 * 2);
    bf16_t* wprojT  = (bf16_t*)alloc((size_t)768 * 768 * 2);
    bf16_t* wff1T   = (bf16_t*)alloc((size_t)3072 * 768 * 2);
    bf16_t* wff2T   = (bf16_t*)alloc((size_t)768 * 3072 * 2);
    bf16_t* qbuf    = (bf16_t*)alloc(ACT * 2);
    bf16_t* kbuf    = (bf16_t*)alloc(ACT * 2);
    bf16_t* vTbuf   = (bf16_t*)alloc(ACT * 2);
    bf16_t* rbuf    = (bf16_t*)alloc(ACT * 2);
    bf16_t* attn_o  = (bf16_t*)alloc(ACT * 2);
    float*  x1f     = (float*)alloc(ACT * 4);
    bf16_t* x1b     = (bf16_t*)alloc(ACT * 2);
    bf16_t* ff1     = (bf16_t*)alloc((size_t)ROWS * 3072 * 2);
    float*  res     = out;  // d_out doubles as fp32 residual scratch

    dim3 tb32(32, 8);

    cvt_bf16_kernel<<<2048, 256, 0, stream>>>(x, xb, (int)ACT);
    qkvr_transpose_kernel<<<dim3(3072 / 32, 768 / 32), tb32, 0, stream>>>(w_qkvr, wqkvrT);
    transpose_cvt_kernel<<<dim3(768 / 32, 768 / 32), tb32, 0, stream>>>(w_proj, wprojT, 768, 768);
    transpose_cvt_kernel<<<dim3(3072 / 32, 768 / 32), tb32, 0, stream>>>(w_ff1, wff1T, 768, 3072);
    transpose_cvt_kernel<<<dim3(768 / 32, 3072 / 32), tb32, 0, stream>>>(w_ff2, wff2T, 3072, 768);

    // QKVR: M=8192, N=3072 -> 32 x 24 = 768 blocks (3 clean CU-rounds)
    gemmsb_kernel<EPI_QKVR, 768, 12, 24><<<768, 512, 0, stream>>>(
        xb, wqkvrT, b_qkvr, qbuf, kbuf, vTbuf, rbuf, nullptr, nullptr, nullptr);

    attn_kernel<<<dim3(SEQ / 64 * BATCH * HEADS), 256, 0, stream>>>(qbuf, kbuf, vTbuf, rbuf, attn_o);

    // PROJ: M=8192, N=768 -> 32 x 6 = 192 blocks
    gemmsb_kernel<EPI_PROJ, 768, 12, 6><<<192, 512, 0, stream>>>(
        attn_o, wprojT, b_proj, nullptr, nullptr, nullptr, nullptr, x, res, nullptr);
    ln_kernel<<<2048, 256, 0, stream>>>(res, ln1_g, ln1_b, x1f, x1b);

    // FF1+GELU: M=8192, N=3072
    gemmsb_kernel<EPI_GELU, 768, 12, 24><<<768, 512, 0, stream>>>(
        x1b, wff1T, b_ff1, nullptr, nullptr, nullptr, nullptr, nullptr, nullptr, ff1);

    // FF2: M=8192, N=768, K=3072 (48 K-tiles)
    gemmsb_kernel<EPI_FF2, 3072, 48, 6><<<192, 512, 0, stream>>>(
        ff1, wff2T, b_ff2, nullptr, nullptr, nullptr, nullptr, x1f, res, nullptr);
    ln_kernel<<<2048, 256, 0, stream>>>(res, ln2_g, ln2_b, out, nullptr);

    (void)in_sizes; (void)n_in; (void)out_size; (void)ws_size;
}